// Round 13
// baseline (115.329 us; speedup 1.0000x reference)
//
#include <hip/hip_runtime.h>
#include <cstdint>
#include <cstddef>

// NetGrad J = W5 D4 W4 D3 W3 D2 W2 D1 W1, output [B,3,64].
// BARRIER-FREE design: one 64-thread block (one wave) owns one 16-sample
// chain end-to-end. Chain state C[48][256] f16 lives in REGISTERS as MFMA
// A-fragments (96 VGPRs). LDS = private per-wave relayout scratch
// (D-layout epilogue writes -> A-fragment reads; wave-internal, no
// __syncthreads anywhere). G1..G3 round-trip HBM as packed f32; G4 fused
// into the L4+expand loop. B-fragments read straight from L2 weight tables.
// No barriers => no vmcnt(0) drains => loads pipeline across phases.

typedef _Float16 half_t;
typedef __attribute__((ext_vector_type(8))) _Float16 half8;
typedef __attribute__((ext_vector_type(4))) float f32x4;

#define MFMA16(a, b, c) __builtin_amdgcn_mfma_f32_16x16x32_f16(a, b, c, 0, 0, 0)

constexpr int Bsz = 8192;
constexpr int LDA = 264;          // LDS scratch row stride in halves (528 B)

// ---------------- prep: f16 tables, native + transposed ----------------
__global__ __launch_bounds__(256)
void prep_split(const float* __restrict__ W1, const float* __restrict__ W2,
                const float* __restrict__ W3, const float* __restrict__ W4,
                half_t* W1h, half_t* T1h, half_t* W2h, half_t* T2h,
                half_t* W3h, half_t* T3h, half_t* W4h, half_t* T4h)
{
    __shared__ float tile[32][33];
    const int bid = blockIdx.x;
    const float* src; half_t *sh, *th; int C, bx, by;
    if (bid < 16) {
        src = W1; sh = W1h; th = T1h;
        C = 64; bx = bid & 1; by = bid >> 1;
    } else {
        const int q = bid - 16, j = q >> 6, lo = q & 63;
        bx = lo & 7; by = lo >> 3; C = 256;
        if (j == 0)      { src = W2; sh = W2h; th = T2h; }
        else if (j == 1) { src = W3; sh = W3h; th = T3h; }
        else             { src = W4; sh = W4h; th = T4h; }
    }
    const int R = 256;
    const int tx = threadIdx.x & 31, ty = threadIdx.x >> 5;
    #pragma unroll
    for (int i = 0; i < 32; i += 8) {
        const size_t o = (size_t)(by * 32 + ty + i) * C + bx * 32 + tx;
        const float v = src[o];
        tile[ty + i][tx] = v;
        sh[o] = (half_t)v;
    }
    __syncthreads();
    #pragma unroll
    for (int i = 0; i < 32; i += 8) {
        const float v = tile[tx][ty + i];
        const size_t o = (size_t)(bx * 32 + ty + i) * R + by * 32 + tx;
        th[o] = (half_t)v;
    }
}

// ---------------- fwd 256-K layer: H' = elu(H @ W^T + b); G -> global f32 ----------------
__device__ __forceinline__
void fwd256(half8 (&H)[8], half_t* __restrict__ S,
            const half_t* __restrict__ Wt, const float* __restrict__ bias,
            float* __restrict__ Gl, int lr, int g, int lane)
{
    #pragma unroll 2
    for (int J = 0; J < 16; ++J) {
        f32x4 acc = {};
        #pragma unroll
        for (int cc = 0; cc < 8; ++cc) {
            const half8 b = *(const half8*)(Wt + (size_t)(J * 16 + lr) * 256 + cc * 32 + g * 8);
            acc = MFMA16(H[cc], b, acc);
        }
        const float bb = bias[J * 16 + lr];
        f32x4 gv;
        #pragma unroll
        for (int r = 0; r < 4; ++r) {
            const float pre = acc[r] + bb;
            float gg, h;
            if (pre > 0.f) { gg = 1.f; h = pre; }
            else           { gg = __expf(pre); h = gg - 1.f; }
            gv[r] = gg;
            S[(4 * g + r) * LDA + J * 16 + lr] = (half_t)h;   // D-layout
        }
        *(f32x4*)(Gl + (J * 64 + lane) * 4) = gv;
    }
    #pragma unroll
    for (int cc = 0; cc < 8; ++cc)                             // A-frag readback
        H[cc] = *(const half8*)&S[lr * LDA + cc * 32 + g * 8];
}

// ---------------- bwd step: C = relayout((C @ T^T) * G) ----------------
__device__ __forceinline__
void bwdstep(half8 (&C)[3][8], half_t* __restrict__ S,
             const half_t* __restrict__ Tt, const float* __restrict__ Gl,
             int lr, int g, int lane)
{
    #pragma unroll 2
    for (int J = 0; J < 16; ++J) {
        f32x4 acc[3] = {};
        #pragma unroll
        for (int cc = 0; cc < 8; ++cc) {
            const half8 b = *(const half8*)(Tt + (size_t)(J * 16 + lr) * 256 + cc * 32 + g * 8);
            #pragma unroll
            for (int t = 0; t < 3; ++t)
                acc[t] = MFMA16(C[t][cc], b, acc[t]);
        }
        const f32x4 gv = *(const f32x4*)(Gl + (J * 64 + lane) * 4);
        #pragma unroll
        for (int t = 0; t < 3; ++t)
            #pragma unroll
            for (int r = 0; r < 4; ++r)
                S[(t * 16 + 4 * g + r) * LDA + J * 16 + lr] = (half_t)(acc[t][r] * gv[r]);
    }
    #pragma unroll
    for (int t = 0; t < 3; ++t)
        #pragma unroll
        for (int cc = 0; cc < 8; ++cc)
            C[t][cc] = *(const half8*)&S[(t * 16 + lr) * LDA + cc * 32 + g * 8];
}

// ---------------- one wave = one 16-sample chain, no barriers ----------------
__global__ __launch_bounds__(64, 1)
void netgrad_wave(const float* __restrict__ x,
                  const half_t* __restrict__ W1h, const float* __restrict__ b1,
                  const half_t* __restrict__ W2h, const float* __restrict__ b2,
                  const half_t* __restrict__ W3h, const float* __restrict__ b3,
                  const half_t* __restrict__ W4h, const float* __restrict__ b4,
                  const float* __restrict__ W5,
                  const half_t* __restrict__ T4h, const half_t* __restrict__ T3h,
                  const half_t* __restrict__ T2h, const half_t* __restrict__ T1h,
                  float* __restrict__ Gbuf, float* __restrict__ out)
{
    __shared__ half_t S[48 * LDA];         // private per-wave relayout scratch
    const int lane = threadIdx.x;
    const int lr = lane & 15, g = lane >> 4;
    const int m0s = blockIdx.x * 16;
    float* Gc = Gbuf + (size_t)blockIdx.x * 3 * 4096;   // [layer][J][lane][4] f32

    half8 H[8];

    // ---- L1 (K=64): A straight from x ----
    {
        #pragma unroll
        for (int c2 = 0; c2 < 2; ++c2) {
            const float* xp = x + (size_t)(m0s + lr) * 64 + c2 * 32 + g * 8;
            const float4 v0 = *(const float4*)xp;
            const float4 v1 = *(const float4*)(xp + 4);
            half8 a;
            a[0] = (half_t)v0.x; a[1] = (half_t)v0.y;
            a[2] = (half_t)v0.z; a[3] = (half_t)v0.w;
            a[4] = (half_t)v1.x; a[5] = (half_t)v1.y;
            a[6] = (half_t)v1.z; a[7] = (half_t)v1.w;
            H[c2] = a;
        }
        #pragma unroll 2
        for (int J = 0; J < 16; ++J) {
            f32x4 acc = {};
            #pragma unroll
            for (int c2 = 0; c2 < 2; ++c2) {
                const half8 b = *(const half8*)(W1h + (size_t)(J * 16 + lr) * 64 + c2 * 32 + g * 8);
                acc = MFMA16(H[c2], b, acc);
            }
            const float bb = b1[J * 16 + lr];
            f32x4 gv;
            #pragma unroll
            for (int r = 0; r < 4; ++r) {
                const float pre = acc[r] + bb;
                float gg, h;
                if (pre > 0.f) { gg = 1.f; h = pre; }
                else           { gg = __expf(pre); h = gg - 1.f; }
                gv[r] = gg;
                S[(4 * g + r) * LDA + J * 16 + lr] = (half_t)h;
            }
            *(f32x4*)(Gc + 0 * 4096 + (J * 64 + lane) * 4) = gv;
        }
        #pragma unroll
        for (int cc = 0; cc < 8; ++cc)
            H[cc] = *(const half8*)&S[lr * LDA + cc * 32 + g * 8];
    }

    // ---- L2, L3 ----
    fwd256(H, S, W2h, b2, Gc + 1 * 4096, lr, g, lane);
    fwd256(H, S, W3h, b3, Gc + 2 * 4096, lr, g, lane);

    // ---- L4 + expand fused: C0[o*16+s][k] = W5[o][k] * elu'(pre4)[s][k] ----
    #pragma unroll 2
    for (int J = 0; J < 16; ++J) {
        f32x4 acc = {};
        #pragma unroll
        for (int cc = 0; cc < 8; ++cc) {
            const half8 b = *(const half8*)(W4h + (size_t)(J * 16 + lr) * 256 + cc * 32 + g * 8);
            acc = MFMA16(H[cc], b, acc);
        }
        const float bb = b4[J * 16 + lr];
        float w5v[3];
        #pragma unroll
        for (int o = 0; o < 3; ++o) w5v[o] = W5[o * 256 + J * 16 + lr];
        #pragma unroll
        for (int r = 0; r < 4; ++r) {
            const float pre = acc[r] + bb;
            const float gg = (pre > 0.f) ? 1.f : __expf(pre);
            #pragma unroll
            for (int o = 0; o < 3; ++o)
                S[(o * 16 + 4 * g + r) * LDA + J * 16 + lr] = (half_t)(w5v[o] * gg);
        }
    }
    half8 C[3][8];
    #pragma unroll
    for (int t = 0; t < 3; ++t)
        #pragma unroll
        for (int cc = 0; cc < 8; ++cc)
            C[t][cc] = *(const half8*)&S[(t * 16 + lr) * LDA + cc * 32 + g * 8];

    // ---- backward chain ----
    bwdstep(C, S, T4h, Gc + 2 * 4096, lr, g, lane);   // * G3
    bwdstep(C, S, T3h, Gc + 1 * 4096, lr, g, lane);   // * G2
    bwdstep(C, S, T2h, Gc + 0 * 4096, lr, g, lane);   // * G1

    // ---- final: out = C @ T1^T  (no scale) ----
    #pragma unroll
    for (int Jf = 0; Jf < 4; ++Jf) {
        f32x4 acc[3] = {};
        #pragma unroll
        for (int cc = 0; cc < 8; ++cc) {
            const half8 b = *(const half8*)(T1h + (size_t)(Jf * 16 + lr) * 256 + cc * 32 + g * 8);
            #pragma unroll
            for (int t = 0; t < 3; ++t)
                acc[t] = MFMA16(C[t][cc], b, acc[t]);
        }
        #pragma unroll
        for (int t = 0; t < 3; ++t)
            #pragma unroll
            for (int r = 0; r < 4; ++r)
                out[((size_t)(m0s + 4 * g + r) * 3 + t) * 64 + Jf * 16 + lr] = acc[t][r];
    }
}

extern "C" void kernel_launch(void* const* d_in, const int* in_sizes, int n_in,
                              void* d_out, int out_size, void* d_ws, size_t ws_size,
                              hipStream_t stream)
{
    const float* x  = (const float*)d_in[0];
    const float* W1 = (const float*)d_in[1];
    const float* b1 = (const float*)d_in[2];
    const float* W2 = (const float*)d_in[3];
    const float* b2 = (const float*)d_in[4];
    const float* W3 = (const float*)d_in[5];
    const float* b3 = (const float*)d_in[6];
    const float* W4 = (const float*)d_in[7];
    const float* b4 = (const float*)d_in[8];
    const float* W5 = (const float*)d_in[9];

    // ---- workspace carve: f16 tables (~0.9 MB) + G f32 (24 MB) ----
    char* p = (char*)d_ws;
    half_t* W1h = (half_t*)p; p += 256 * 64 * 2;
    half_t* T1h = (half_t*)p; p += 64 * 256 * 2;
    half_t* W2h = (half_t*)p; p += 256 * 256 * 2;
    half_t* T2h = (half_t*)p; p += 256 * 256 * 2;
    half_t* W3h = (half_t*)p; p += 256 * 256 * 2;
    half_t* T3h = (half_t*)p; p += 256 * 256 * 2;
    half_t* W4h = (half_t*)p; p += 256 * 256 * 2;
    half_t* T4h = (half_t*)p; p += 256 * 256 * 2;
    float* Gbuf = (float*)p;   // 512 chains * 3 layers * 4096 f32 = 24 MB

    prep_split<<<208, 256, 0, stream>>>(W1, W2, W3, W4,
        W1h, T1h, W2h, T2h, W3h, T3h, W4h, T4h);

    netgrad_wave<<<Bsz / 16, 64, 0, stream>>>(x,
        W1h, b1,  W2h, b2,  W3h, b3,  W4h, b4,
        W5,  T4h, T3h, T2h, T1h,
        Gbuf, (float*)d_out);
}

// Round 14
// 43.775 us; speedup vs baseline: 2.6346x; 2.6346x over previous
//
#include <hip/hip_runtime.h>
#include <cstdint>
#include <cstddef>

// NetGrad J = W5 D4 W4 D3 W3 D2 W2 D1 W1, output [B,3,64].
// 32 samples/block, 4 waves (col-split only, FN=4): each wave carries SIX
// A-fragments (3 outputs x 2 sample-halves) per bwd step, so each 32KB/phase
// of weight-fragment traffic is amortized over 2x rows vs r11 (the measured
// invariant cost). 1 block/CU, grid 256. Permuted column storage (conflict-
// free half4 LDS writes), all-f16 MFMA, G1..G4 in registers.

typedef _Float16 half_t;
typedef __attribute__((ext_vector_type(4))) _Float16 half4;
typedef __attribute__((ext_vector_type(8))) _Float16 half8;
typedef __attribute__((ext_vector_type(4))) float f32x4;

#define MFMA16(a, b, c) __builtin_amdgcn_mfma_f32_16x16x32_f16(a, b, c, 0, 0, 0)

constexpr int Bsz = 8192;
constexpr int LDA = 264;          // LDS row stride in halves (528 B)

// logical k held at storage position p (bijection on 0..255)
__device__ __forceinline__ int kofp(int p) {
    return (p & 0xC0) | ((p & 3) << 4) | ((p >> 2) & 15);
}

// ---------------- prep: gather-permute all weight tables to f16 ----------------
__global__ __launch_bounds__(256)
void prep(const float* __restrict__ W1, const float* __restrict__ W2,
          const float* __restrict__ W3, const float* __restrict__ W4,
          half_t* W1h, half_t* T1p,
          half_t* W2p, half_t* W3p, half_t* W4p,
          half_t* T2p, half_t* T3p, half_t* T4p)
{
    int idx = blockIdx.x * 256 + threadIdx.x;
    if (idx < 16384) { W1h[idx] = (half_t)W1[idx]; return; }
    idx -= 16384;
    if (idx < 16384) {
        const int j = idx >> 8, p = idx & 255;
        T1p[idx] = (half_t)W1[kofp(p) * 64 + j];
        return;
    }
    idx -= 16384;
    if (idx >= 6 * 65536) return;
    const int t = idx >> 16, i = idx & 65535;
    const int c = i >> 8, p = i & 255, k = kofp(p);
    switch (t) {
        case 0: W2p[i] = (half_t)W2[c * 256 + k]; break;
        case 1: W3p[i] = (half_t)W3[c * 256 + k]; break;
        case 2: W4p[i] = (half_t)W4[c * 256 + k]; break;
        case 3: T2p[i] = (half_t)W2[k * 256 + c]; break;
        case 4: T3p[i] = (half_t)W3[k * 256 + c]; break;
        case 5: T4p[i] = (half_t)W4[k * 256 + c]; break;
    }
}

// ---------------- fwd layer (K=256): 32 samples, 2 A-frags/wave ----------------
template<bool WRITE_H>
__device__ __forceinline__
void fwd_layer_p(const half_t* __restrict__ Ard, half_t* __restrict__ Awr,
                 const half_t* __restrict__ Wp, const float* __restrict__ bias,
                 float gout[2][4][4], int n0w, int lr, int kgrp, int pbase)
{
    f32x4 acc[2][4] = {};
    #pragma unroll
    for (int kc = 0; kc < 8; ++kc) {
        const int ko = kc * 32 + kgrp * 8;
        half8 b[4];
        #pragma unroll
        for (int fn = 0; fn < 4; ++fn)
            b[fn] = *(const half8*)(Wp + (size_t)(n0w + fn * 16 + lr) * 256 + ko);
        half8 a[2];
        #pragma unroll
        for (int m = 0; m < 2; ++m)
            a[m] = *(const half8*)&Ard[(m * 16 + lr) * LDA + ko];
        __builtin_amdgcn_s_setprio(1);
        #pragma unroll
        for (int fn = 0; fn < 4; ++fn)
            #pragma unroll
            for (int m = 0; m < 2; ++m)
                acc[m][fn] = MFMA16(a[m], b[fn], acc[m][fn]);
        __builtin_amdgcn_s_setprio(0);
    }
    float hv[2][4][4];
    #pragma unroll
    for (int fn = 0; fn < 4; ++fn) {
        const float bc = bias[n0w + fn * 16 + lr];
        #pragma unroll
        for (int m = 0; m < 2; ++m)
            #pragma unroll
            for (int r = 0; r < 4; ++r) {
                const float pre = acc[m][fn][r] + bc;
                float g, h;
                if (pre > 0.f) { g = 1.f; h = pre; }
                else           { g = __expf(pre); h = g - 1.f; }
                gout[m][fn][r] = g;
                hv[m][r][fn] = h;
            }
    }
    if constexpr (WRITE_H) {
        #pragma unroll
        for (int m = 0; m < 2; ++m)
            #pragma unroll
            for (int r = 0; r < 4; ++r) {
                half4 w = {(half_t)hv[m][r][0], (half_t)hv[m][r][1],
                           (half_t)hv[m][r][2], (half_t)hv[m][r][3]};
                *(half4*)&Awr[(m * 16 + kgrp * 4 + r) * LDA + pbase] = w;
            }
        __syncthreads();
    }
}

// ---------------- bwd mid step: 6 A-frags/wave (3 o x 2 m) ----------------
__device__ __forceinline__
void bwd_mid(const half_t* __restrict__ Crd, half_t* __restrict__ Cwr,
             const half_t* __restrict__ Tp, const float gpre[2][4][4],
             int n0w, int lr, int kgrp, int pbase)
{
    f32x4 acc[3][2][4] = {};
    #pragma unroll
    for (int kc = 0; kc < 8; ++kc) {
        const int ko = kc * 32 + kgrp * 8;
        half8 b[4];
        #pragma unroll
        for (int fn = 0; fn < 4; ++fn)
            b[fn] = *(const half8*)(Tp + (size_t)(n0w + fn * 16 + lr) * 256 + ko);
        half8 a[3][2];
        #pragma unroll
        for (int o = 0; o < 3; ++o)
            #pragma unroll
            for (int m = 0; m < 2; ++m)
                a[o][m] = *(const half8*)&Crd[(o * 32 + m * 16 + lr) * LDA + ko];
        __builtin_amdgcn_s_setprio(1);
        #pragma unroll
        for (int fn = 0; fn < 4; ++fn)
            #pragma unroll
            for (int o = 0; o < 3; ++o)
                #pragma unroll
                for (int m = 0; m < 2; ++m)
                    acc[o][m][fn] = MFMA16(a[o][m], b[fn], acc[o][m][fn]);
        __builtin_amdgcn_s_setprio(0);
    }
    #pragma unroll
    for (int o = 0; o < 3; ++o)
        #pragma unroll
        for (int m = 0; m < 2; ++m)
            #pragma unroll
            for (int r = 0; r < 4; ++r) {
                half4 w = {(half_t)(acc[o][m][0][r] * gpre[m][0][r]),
                           (half_t)(acc[o][m][1][r] * gpre[m][1][r]),
                           (half_t)(acc[o][m][2][r] * gpre[m][2][r]),
                           (half_t)(acc[o][m][3][r] * gpre[m][3][r])};
                *(half4*)&Cwr[(o * 32 + m * 16 + kgrp * 4 + r) * LDA + pbase] = w;
            }
    __syncthreads();
}

// ---------------- fully fused forward+backward, 32 samples / 4 waves ----------------
__global__ __launch_bounds__(256, 1)
void netgrad_fused(const float* __restrict__ x,
                   const half_t* __restrict__ W1h, const float* __restrict__ b1,
                   const half_t* __restrict__ W2p, const float* __restrict__ b2,
                   const half_t* __restrict__ W3p, const float* __restrict__ b3,
                   const half_t* __restrict__ W4p, const float* __restrict__ b4,
                   const float* __restrict__ W5,
                   const half_t* __restrict__ T4p, const half_t* __restrict__ T3p,
                   const half_t* __restrict__ T2p, const half_t* __restrict__ T1p,
                   float* __restrict__ out)
{
    __shared__ half_t CA[96 * LDA];
    __shared__ half_t CB[96 * LDA];
    const int tid  = threadIdx.x;
    const int m0s  = blockIdx.x * 32;
    const int lane = tid & 63, lr = lane & 15, kgrp = lane >> 4;
    const int wn   = tid >> 6;             // wave = col span 0..3
    const int n0w  = wn * 64;
    const int pbase = (lr << 2) | (wn << 6);

    float G1r[2][4][4], G2r[2][4][4], G3r[2][4][4], G4r[2][4][4];

    // ---- L1 (K=64): A straight from x; 2 sample-half frags ----
    {
        half8 a[2][2];
        #pragma unroll
        for (int m = 0; m < 2; ++m)
            #pragma unroll
            for (int c2 = 0; c2 < 2; ++c2) {
                const float* xp = x + (size_t)(m0s + m * 16 + lr) * 64 + c2 * 32 + kgrp * 8;
                const float4 v0 = *(const float4*)xp;
                const float4 v1 = *(const float4*)(xp + 4);
                half8 t;
                t[0] = (half_t)v0.x; t[1] = (half_t)v0.y;
                t[2] = (half_t)v0.z; t[3] = (half_t)v0.w;
                t[4] = (half_t)v1.x; t[5] = (half_t)v1.y;
                t[6] = (half_t)v1.z; t[7] = (half_t)v1.w;
                a[m][c2] = t;
            }
        f32x4 acc[2][4] = {};
        #pragma unroll
        for (int c2 = 0; c2 < 2; ++c2)
            #pragma unroll
            for (int fn = 0; fn < 4; ++fn) {
                const half8 b = *(const half8*)(W1h + (size_t)(n0w + fn * 16 + lr) * 64
                                                + c2 * 32 + kgrp * 8);
                #pragma unroll
                for (int m = 0; m < 2; ++m)
                    acc[m][fn] = MFMA16(a[m][c2], b, acc[m][fn]);
            }
        float hv[2][4][4];
        #pragma unroll
        for (int fn = 0; fn < 4; ++fn) {
            const float bc = b1[n0w + fn * 16 + lr];
            #pragma unroll
            for (int m = 0; m < 2; ++m)
                #pragma unroll
                for (int r = 0; r < 4; ++r) {
                    const float pre = acc[m][fn][r] + bc;
                    float g, h;
                    if (pre > 0.f) { g = 1.f; h = pre; }
                    else           { g = __expf(pre); h = g - 1.f; }
                    G1r[m][fn][r] = g;
                    hv[m][r][fn] = h;
                }
        }
        #pragma unroll
        for (int m = 0; m < 2; ++m)
            #pragma unroll
            for (int r = 0; r < 4; ++r) {
                half4 w = {(half_t)hv[m][r][0], (half_t)hv[m][r][1],
                           (half_t)hv[m][r][2], (half_t)hv[m][r][3]};
                *(half4*)&CA[(m * 16 + kgrp * 4 + r) * LDA + pbase] = w;
            }
        __syncthreads();
    }

    // ---- L2..L4: H ping-pong CA->CB->CA ----
    fwd_layer_p<true >(CA, CB, W2p, b2, G2r, n0w, lr, kgrp, pbase);
    fwd_layer_p<true >(CB, CA, W3p, b3, G3r, n0w, lr, kgrp, pbase);
    fwd_layer_p<false>(CA, nullptr, W4p, b4, G4r, n0w, lr, kgrp, pbase);

    // ---- expand into CB: CB[o*32+s][k] = W5[o][k] * G4[s][k] ----
    {
        float w5v[3][4];
        #pragma unroll
        for (int fn = 0; fn < 4; ++fn) {
            const int k = n0w + fn * 16 + lr;
            #pragma unroll
            for (int o = 0; o < 3; ++o) w5v[o][fn] = W5[o * 256 + k];
        }
        #pragma unroll
        for (int o = 0; o < 3; ++o)
            #pragma unroll
            for (int m = 0; m < 2; ++m)
                #pragma unroll
                for (int r = 0; r < 4; ++r) {
                    half4 w = {(half_t)(w5v[o][0] * G4r[m][0][r]),
                               (half_t)(w5v[o][1] * G4r[m][1][r]),
                               (half_t)(w5v[o][2] * G4r[m][2][r]),
                               (half_t)(w5v[o][3] * G4r[m][3][r])};
                    *(half4*)&CB[(o * 32 + m * 16 + kgrp * 4 + r) * LDA + pbase] = w;
                }
        __syncthreads();
    }

    // ---- backward chain: CB -> CA -> CB -> CA ----
    bwd_mid(CB, CA, T4p, G3r, n0w, lr, kgrp, pbase);
    bwd_mid(CA, CB, T3p, G2r, n0w, lr, kgrp, pbase);
    bwd_mid(CB, CA, T2p, G1r, n0w, lr, kgrp, pbase);

    // ---- final: CA[96][256] @ T1p^T -> out; each wave 16 cols ----
    {
        const int j = wn * 16 + lr;
        const size_t bcf = (size_t)j * 256;
        f32x4 acc[3][2] = {};
        #pragma unroll
        for (int kc = 0; kc < 8; ++kc) {
            const int ko = kc * 32 + kgrp * 8;
            const half8 b = *(const half8*)(T1p + bcf + ko);
            #pragma unroll
            for (int o = 0; o < 3; ++o)
                #pragma unroll
                for (int m = 0; m < 2; ++m)
                    acc[o][m] = MFMA16(*(const half8*)&CA[(o * 32 + m * 16 + lr) * LDA + ko],
                                       b, acc[o][m]);
        }
        #pragma unroll
        for (int o = 0; o < 3; ++o)
            #pragma unroll
            for (int m = 0; m < 2; ++m)
                #pragma unroll
                for (int r = 0; r < 4; ++r)
                    out[((size_t)(m0s + m * 16 + kgrp * 4 + r) * 3 + o) * 64 + j] = acc[o][m][r];
    }
}

extern "C" void kernel_launch(void* const* d_in, const int* in_sizes, int n_in,
                              void* d_out, int out_size, void* d_ws, size_t ws_size,
                              hipStream_t stream)
{
    const float* x  = (const float*)d_in[0];
    const float* W1 = (const float*)d_in[1];
    const float* b1 = (const float*)d_in[2];
    const float* W2 = (const float*)d_in[3];
    const float* b2 = (const float*)d_in[4];
    const float* W3 = (const float*)d_in[5];
    const float* b3 = (const float*)d_in[6];
    const float* W4 = (const float*)d_in[7];
    const float* b4 = (const float*)d_in[8];
    const float* W5 = (const float*)d_in[9];

    // ---- workspace carve (~0.9 MB f16 tables) ----
    char* p = (char*)d_ws;
    half_t* W1h = (half_t*)p; p += 256 * 64 * 2;
    half_t* T1p = (half_t*)p; p += 64 * 256 * 2;
    half_t* W2p = (half_t*)p; p += 256 * 256 * 2;
    half_t* W3p = (half_t*)p; p += 256 * 256 * 2;
    half_t* W4p = (half_t*)p; p += 256 * 256 * 2;
    half_t* T2p = (half_t*)p; p += 256 * 256 * 2;
    half_t* T3p = (half_t*)p; p += 256 * 256 * 2;
    half_t* T4p = (half_t*)p; p += 256 * 256 * 2;

    const int prep_elems = 16384 + 16384 + 6 * 65536;
    prep<<<(prep_elems + 255) / 256, 256, 0, stream>>>(W1, W2, W3, W4,
        W1h, T1p, W2p, W3p, W4p, T2p, T3p, T4p);

    netgrad_fused<<<Bsz / 32, 256, 0, stream>>>(x,
        W1h, b1,  W2p, b2,  W3p, b3,  W4p, b4,
        W5,  T4p, T3p, T2p, T1p,
        (float*)d_out);
}

// Round 15
// 42.385 us; speedup vs baseline: 2.7210x; 1.0328x over previous
//
#include <hip/hip_runtime.h>
#include <cstdint>
#include <cstddef>

// NetGrad J = W5 D4 W4 D3 W3 D2 W2 D1 W1, output [B,3,64].
// 32 samples/block, 8 waves split by COLUMN only (wn=0..7, 32-col span,
// FN=2), 1 block/CU: keeps r14's minimal weight traffic (one full table
// read per phase, slices distinct across waves) AND gives 2 waves/SIMD so
// one wave's L2 B-loads hide under the other's MFMAs. Each wave carries 6
// A-fragments (3 o x 2 m). Permuted column storage for conflict-free half2
// epilogue writes; weight tables pre-permuted to match. G1..G4 in regs.

typedef _Float16 half_t;
typedef __attribute__((ext_vector_type(2))) _Float16 half2v;
typedef __attribute__((ext_vector_type(8))) _Float16 half8;
typedef __attribute__((ext_vector_type(4))) float f32x4;

#define MFMA16(a, b, c) __builtin_amdgcn_mfma_f32_16x16x32_f16(a, b, c, 0, 0, 0)

constexpr int Bsz = 8192;
constexpr int LDA = 264;          // LDS row stride in halves (528 B)

// logical k at storage position p: p bits [7:5]=wn,[4:1]=lr,[0]=fn
//                                  k bits [7:5]=wn,[4]=fn,[3:0]=lr
__device__ __forceinline__ int kofp(int p) {
    return (p & 0xE0) | ((p & 1) << 4) | ((p >> 1) & 15);
}

// ---------------- prep: gather-permute all weight tables to f16 ----------------
__global__ __launch_bounds__(256)
void prep(const float* __restrict__ W1, const float* __restrict__ W2,
          const float* __restrict__ W3, const float* __restrict__ W4,
          half_t* W1h, half_t* T1p,
          half_t* W2p, half_t* W3p, half_t* W4p,
          half_t* T2p, half_t* T3p, half_t* T4p)
{
    int idx = blockIdx.x * 256 + threadIdx.x;
    if (idx < 16384) { W1h[idx] = (half_t)W1[idx]; return; }
    idx -= 16384;
    if (idx < 16384) {
        const int j = idx >> 8, p = idx & 255;
        T1p[idx] = (half_t)W1[kofp(p) * 64 + j];
        return;
    }
    idx -= 16384;
    if (idx >= 6 * 65536) return;
    const int t = idx >> 16, i = idx & 65535;
    const int c = i >> 8, p = i & 255, k = kofp(p);
    switch (t) {
        case 0: W2p[i] = (half_t)W2[c * 256 + k]; break;
        case 1: W3p[i] = (half_t)W3[c * 256 + k]; break;
        case 2: W4p[i] = (half_t)W4[c * 256 + k]; break;
        case 3: T2p[i] = (half_t)W2[k * 256 + c]; break;
        case 4: T3p[i] = (half_t)W3[k * 256 + c]; break;
        case 5: T4p[i] = (half_t)W4[k * 256 + c]; break;
    }
}

// ---------------- fwd layer (K=256): 2 A-frags (m), FN=2 ----------------
template<bool WRITE_H>
__device__ __forceinline__
void fwd_layer_p(const half_t* __restrict__ Ard, half_t* __restrict__ Awr,
                 const half_t* __restrict__ Wp, const float* __restrict__ bias,
                 float gout[2][2][4], int n0w, int lr, int kgrp, int pb2)
{
    f32x4 acc[2][2] = {};
    #pragma unroll
    for (int kc = 0; kc < 8; ++kc) {
        const int ko = kc * 32 + kgrp * 8;
        half8 b[2];
        #pragma unroll
        for (int fn = 0; fn < 2; ++fn)
            b[fn] = *(const half8*)(Wp + (size_t)(n0w + fn * 16 + lr) * 256 + ko);
        half8 a[2];
        #pragma unroll
        for (int m = 0; m < 2; ++m)
            a[m] = *(const half8*)&Ard[(m * 16 + lr) * LDA + ko];
        __builtin_amdgcn_s_setprio(1);
        #pragma unroll
        for (int fn = 0; fn < 2; ++fn)
            #pragma unroll
            for (int m = 0; m < 2; ++m)
                acc[m][fn] = MFMA16(a[m], b[fn], acc[m][fn]);
        __builtin_amdgcn_s_setprio(0);
    }
    float hv[2][4][2];
    #pragma unroll
    for (int fn = 0; fn < 2; ++fn) {
        const float bc = bias[n0w + fn * 16 + lr];
        #pragma unroll
        for (int m = 0; m < 2; ++m)
            #pragma unroll
            for (int r = 0; r < 4; ++r) {
                const float pre = acc[m][fn][r] + bc;
                float g, h;
                if (pre > 0.f) { g = 1.f; h = pre; }
                else           { g = __expf(pre); h = g - 1.f; }
                gout[m][fn][r] = g;
                hv[m][r][fn] = h;
            }
    }
    if constexpr (WRITE_H) {
        #pragma unroll
        for (int m = 0; m < 2; ++m)
            #pragma unroll
            for (int r = 0; r < 4; ++r) {
                half2v w = {(half_t)hv[m][r][0], (half_t)hv[m][r][1]};
                *(half2v*)&Awr[(m * 16 + kgrp * 4 + r) * LDA + pb2] = w;
            }
        __syncthreads();
    }
}

// ---------------- bwd mid step: 6 A-frags (3 o x 2 m), FN=2 ----------------
__device__ __forceinline__
void bwd_mid(const half_t* __restrict__ Crd, half_t* __restrict__ Cwr,
             const half_t* __restrict__ Tp, const float gpre[2][2][4],
             int n0w, int lr, int kgrp, int pb2)
{
    f32x4 acc[3][2][2] = {};
    #pragma unroll
    for (int kc = 0; kc < 8; ++kc) {
        const int ko = kc * 32 + kgrp * 8;
        half8 b[2];
        #pragma unroll
        for (int fn = 0; fn < 2; ++fn)
            b[fn] = *(const half8*)(Tp + (size_t)(n0w + fn * 16 + lr) * 256 + ko);
        half8 a[3][2];
        #pragma unroll
        for (int o = 0; o < 3; ++o)
            #pragma unroll
            for (int m = 0; m < 2; ++m)
                a[o][m] = *(const half8*)&Crd[(o * 32 + m * 16 + lr) * LDA + ko];
        __builtin_amdgcn_s_setprio(1);
        #pragma unroll
        for (int fn = 0; fn < 2; ++fn)
            #pragma unroll
            for (int o = 0; o < 3; ++o)
                #pragma unroll
                for (int m = 0; m < 2; ++m)
                    acc[o][m][fn] = MFMA16(a[o][m], b[fn], acc[o][m][fn]);
        __builtin_amdgcn_s_setprio(0);
    }
    #pragma unroll
    for (int o = 0; o < 3; ++o)
        #pragma unroll
        for (int m = 0; m < 2; ++m)
            #pragma unroll
            for (int r = 0; r < 4; ++r) {
                half2v w = {(half_t)(acc[o][m][0][r] * gpre[m][0][r]),
                            (half_t)(acc[o][m][1][r] * gpre[m][1][r])};
                *(half2v*)&Cwr[(o * 32 + m * 16 + kgrp * 4 + r) * LDA + pb2] = w;
            }
    __syncthreads();
}

// ---------------- fully fused forward+backward, 32 samples / 8 waves ----------------
__global__ __launch_bounds__(512, 1)
void netgrad_fused(const float* __restrict__ x,
                   const half_t* __restrict__ W1h, const float* __restrict__ b1,
                   const half_t* __restrict__ W2p, const float* __restrict__ b2,
                   const half_t* __restrict__ W3p, const float* __restrict__ b3,
                   const half_t* __restrict__ W4p, const float* __restrict__ b4,
                   const float* __restrict__ W5,
                   const half_t* __restrict__ T4p, const half_t* __restrict__ T3p,
                   const half_t* __restrict__ T2p, const half_t* __restrict__ T1p,
                   float* __restrict__ out)
{
    __shared__ half_t CA[96 * LDA];
    __shared__ half_t CB[96 * LDA];
    const int tid  = threadIdx.x;
    const int m0s  = blockIdx.x * 32;
    const int lane = tid & 63, lr = lane & 15, kgrp = lane >> 4;
    const int wn   = tid >> 6;             // wave = col span 0..7
    const int n0w  = wn * 32;
    const int pb2  = (wn << 5) | (lr << 1);   // permuted half2 write base

    float G1r[2][2][4], G2r[2][2][4], G3r[2][2][4], G4r[2][2][4];

    // ---- L1 (K=64): A straight from x; 2 sample-half frags ----
    {
        half8 a[2][2];
        #pragma unroll
        for (int m = 0; m < 2; ++m)
            #pragma unroll
            for (int c2 = 0; c2 < 2; ++c2) {
                const float* xp = x + (size_t)(m0s + m * 16 + lr) * 64 + c2 * 32 + kgrp * 8;
                const float4 v0 = *(const float4*)xp;
                const float4 v1 = *(const float4*)(xp + 4);
                half8 t;
                t[0] = (half_t)v0.x; t[1] = (half_t)v0.y;
                t[2] = (half_t)v0.z; t[3] = (half_t)v0.w;
                t[4] = (half_t)v1.x; t[5] = (half_t)v1.y;
                t[6] = (half_t)v1.z; t[7] = (half_t)v1.w;
                a[m][c2] = t;
            }
        f32x4 acc[2][2] = {};
        #pragma unroll
        for (int c2 = 0; c2 < 2; ++c2)
            #pragma unroll
            for (int fn = 0; fn < 2; ++fn) {
                const half8 b = *(const half8*)(W1h + (size_t)(n0w + fn * 16 + lr) * 64
                                                + c2 * 32 + kgrp * 8);
                #pragma unroll
                for (int m = 0; m < 2; ++m)
                    acc[m][fn] = MFMA16(a[m][c2], b, acc[m][fn]);
            }
        float hv[2][4][2];
        #pragma unroll
        for (int fn = 0; fn < 2; ++fn) {
            const float bc = b1[n0w + fn * 16 + lr];
            #pragma unroll
            for (int m = 0; m < 2; ++m)
                #pragma unroll
                for (int r = 0; r < 4; ++r) {
                    const float pre = acc[m][fn][r] + bc;
                    float g, h;
                    if (pre > 0.f) { g = 1.f; h = pre; }
                    else           { g = __expf(pre); h = g - 1.f; }
                    G1r[m][fn][r] = g;
                    hv[m][r][fn] = h;
                }
        }
        #pragma unroll
        for (int m = 0; m < 2; ++m)
            #pragma unroll
            for (int r = 0; r < 4; ++r) {
                half2v w = {(half_t)hv[m][r][0], (half_t)hv[m][r][1]};
                *(half2v*)&CA[(m * 16 + kgrp * 4 + r) * LDA + pb2] = w;
            }
        __syncthreads();
    }

    // ---- L2..L4: H ping-pong CA->CB->CA ----
    fwd_layer_p<true >(CA, CB, W2p, b2, G2r, n0w, lr, kgrp, pb2);
    fwd_layer_p<true >(CB, CA, W3p, b3, G3r, n0w, lr, kgrp, pb2);
    fwd_layer_p<false>(CA, nullptr, W4p, b4, G4r, n0w, lr, kgrp, pb2);

    // ---- expand into CB: CB[o*32+s][k] = W5[o][k] * G4[s][k] ----
    {
        float w5v[3][2];
        #pragma unroll
        for (int fn = 0; fn < 2; ++fn) {
            const int k = n0w + fn * 16 + lr;
            #pragma unroll
            for (int o = 0; o < 3; ++o) w5v[o][fn] = W5[o * 256 + k];
        }
        #pragma unroll
        for (int o = 0; o < 3; ++o)
            #pragma unroll
            for (int m = 0; m < 2; ++m)
                #pragma unroll
                for (int r = 0; r < 4; ++r) {
                    half2v w = {(half_t)(w5v[o][0] * G4r[m][0][r]),
                                (half_t)(w5v[o][1] * G4r[m][1][r])};
                    *(half2v*)&CB[(o * 32 + m * 16 + kgrp * 4 + r) * LDA + pb2] = w;
                }
        __syncthreads();
    }

    // ---- backward chain: CB -> CA -> CB -> CA ----
    bwd_mid(CB, CA, T4p, G3r, n0w, lr, kgrp, pb2);
    bwd_mid(CA, CB, T3p, G2r, n0w, lr, kgrp, pb2);
    bwd_mid(CB, CA, T2p, G1r, n0w, lr, kgrp, pb2);

    // ---- final: CA[96][256] @ T1p^T -> out ----
    // waves 0-3: o in {0,1}; waves 4-7: o=2. col = (wn&3)*16 + lr.
    {
        const int j = (wn & 3) * 16 + lr;
        const size_t bcf = (size_t)j * 256;
        if (wn < 4) {
            f32x4 acc[2][2] = {};
            #pragma unroll
            for (int kc = 0; kc < 8; ++kc) {
                const int ko = kc * 32 + kgrp * 8;
                const half8 b = *(const half8*)(T1p + bcf + ko);
                #pragma unroll
                for (int o = 0; o < 2; ++o)
                    #pragma unroll
                    for (int m = 0; m < 2; ++m)
                        acc[o][m] = MFMA16(*(const half8*)&CA[(o * 32 + m * 16 + lr) * LDA + ko],
                                           b, acc[o][m]);
            }
            #pragma unroll
            for (int o = 0; o < 2; ++o)
                #pragma unroll
                for (int m = 0; m < 2; ++m)
                    #pragma unroll
                    for (int r = 0; r < 4; ++r)
                        out[((size_t)(m0s + m * 16 + kgrp * 4 + r) * 3 + o) * 64 + j] = acc[o][m][r];
        } else {
            f32x4 acc[2] = {};
            #pragma unroll
            for (int kc = 0; kc < 8; ++kc) {
                const int ko = kc * 32 + kgrp * 8;
                const half8 b = *(const half8*)(T1p + bcf + ko);
                #pragma unroll
                for (int m = 0; m < 2; ++m)
                    acc[m] = MFMA16(*(const half8*)&CA[(2 * 32 + m * 16 + lr) * LDA + ko],
                                    b, acc[m]);
            }
            #pragma unroll
            for (int m = 0; m < 2; ++m)
                #pragma unroll
                for (int r = 0; r < 4; ++r)
                    out[((size_t)(m0s + m * 16 + kgrp * 4 + r) * 3 + 2) * 64 + j] = acc[m][r];
        }
    }
}

extern "C" void kernel_launch(void* const* d_in, const int* in_sizes, int n_in,
                              void* d_out, int out_size, void* d_ws, size_t ws_size,
                              hipStream_t stream)
{
    const float* x  = (const float*)d_in[0];
    const float* W1 = (const float*)d_in[1];
    const float* b1 = (const float*)d_in[2];
    const float* W2 = (const float*)d_in[3];
    const float* b2 = (const float*)d_in[4];
    const float* W3 = (const float*)d_in[5];
    const float* b3 = (const float*)d_in[6];
    const float* W4 = (const float*)d_in[7];
    const float* b4 = (const float*)d_in[8];
    const float* W5 = (const float*)d_in[9];

    // ---- workspace carve (~0.9 MB f16 tables) ----
    char* p = (char*)d_ws;
    half_t* W1h = (half_t*)p; p += 256 * 64 * 2;
    half_t* T1p = (half_t*)p; p += 64 * 256 * 2;
    half_t* W2p = (half_t*)p; p += 256 * 256 * 2;
    half_t* W3p = (half_t*)p; p += 256 * 256 * 2;
    half_t* W4p = (half_t*)p; p += 256 * 256 * 2;
    half_t* T2p = (half_t*)p; p += 256 * 256 * 2;
    half_t* T3p = (half_t*)p; p += 256 * 256 * 2;
    half_t* T4p = (half_t*)p; p += 256 * 256 * 2;

    const int prep_elems = 16384 + 16384 + 6 * 65536;
    prep<<<(prep_elems + 255) / 256, 256, 0, stream>>>(W1, W2, W3, W4,
        W1h, T1p, W2p, W3p, W4p, T2p, T3p, T4p);

    netgrad_fused<<<Bsz / 32, 512, 0, stream>>>(x,
        W1h, b1,  W2p, b2,  W3p, b3,  W4p, b4,
        W5,  T4p, T3p, T2p, T1p,
        (float*)d_out);
}